// Round 7
// baseline (304.847 us; speedup 1.0000x reference)
//
#include <hip/hip_runtime.h>
#include <hip/hip_bf16.h>

// WhaleAttention: B=2, N=2048, C=1024, H=16, D=64, SCALE=1/8
// R7: kp = [hs|pos]·[Wk|Wp]^T single K=2048 GEMM (fuse_kpc eliminated);
// c = hp·Wc^T via prep'd 16-row weight; v-transpose via LDS-coalesced
// epilogue; attn = R4 32q/wave + fixed-base exp2 + split-K(x2) + merge.

typedef short bf16x8 __attribute__((ext_vector_type(8)));
typedef float f32x4 __attribute__((ext_vector_type(4)));

#define BB 2
#define NN 2048
#define CC 1024
#define HH 16
#define DD 64
#define MM (BB * NN)      // 4096 rows
#define SC2E 0.18033688f  // SCALE * log2(e)

__device__ __forceinline__ unsigned short f2bf(float f) {
    union { float f; unsigned int u; } x; x.f = f;
    unsigned int r = x.u + 0x7FFFu + ((x.u >> 16) & 1u);
    return (unsigned short)(r >> 16);
}

__device__ __forceinline__ float bf2f(unsigned short s) {
    union { unsigned int u; float f; } x; x.u = ((unsigned int)s) << 16;
    return x.f;
}

__device__ __forceinline__ unsigned int pk2(float a, float b) {
    __hip_bfloat162 h = __float22bfloat162_rn(make_float2(a, b));
    unsigned int u; __builtin_memcpy(&u, &h, 4); return u;
}

typedef __attribute__((address_space(1))) const unsigned int* gas1_t;
typedef __attribute__((address_space(3))) unsigned int* las3_t;

__device__ __forceinline__ void gload_lds16(const unsigned short* g, unsigned short* l) {
    __builtin_amdgcn_global_load_lds((gas1_t)g, (las3_t)l, 16, 0, 0);
}

// ---------------------------------------------------------------- cast kernel
// 7 segments, strided dst (enables hp = [hs|pos], wkp = [Wk|Wp] concat).
struct CastArgs {
    const float* src[7];
    unsigned short* dst[7];
    int rows[7];
    int stride[7];   // dst row stride (bf16 elems)
    int col0[7];     // dst col offset
};
__global__ __launch_bounds__(256) void cast_all(CastArgs a) {
    const int seg = blockIdx.y, row = blockIdx.x;
    if (row >= a.rows[seg]) return;
    const int c4 = threadIdx.x;                      // 256 float4 = 1024 f32/row
    float4 v = ((const float4*)a.src[seg])[row * 256 + c4];
    uint2 u;
    u.x = pk2(v.x, v.y);
    u.y = pk2(v.z, v.w);
    ((uint2*)(a.dst[seg] + (size_t)row * a.stride[seg] + a.col0[seg]))[c4] = u;
}

// ---------------------------------------------------------------- prep kernel
// Wc[h][0:1024]  = SC2E * sum_d u[h,d] * Wk[h*64+d][:]
// Wc[h][1024:]   = SC2E * sum_d v[h,d] * Wp[h*64+d][:]     (fp32)
// cu[h]          = SC2E * sum_d u[h,d] * bk[h*64+d]
__global__ __launch_bounds__(256) void prep(const float* __restrict__ Wk,
                                            const float* __restrict__ Wp,
                                            const float* __restrict__ pbu,
                                            const float* __restrict__ pbv,
                                            const float* __restrict__ bk,
                                            float* __restrict__ Wc,
                                            float* __restrict__ cu) {
    const int h = blockIdx.x, half = blockIdx.y;
    const float* W = half ? Wp : Wk;
    const float* uv = half ? pbv : pbu;
    const int c0 = threadIdx.x * 4;
    float a0 = 0.f, a1 = 0.f, a2 = 0.f, a3 = 0.f;
    for (int d = 0; d < 64; ++d) {
        const float wgt = uv[h * 64 + d] * SC2E;
        float4 wv = *(const float4*)&W[(size_t)(h * 64 + d) * 1024 + c0];
        a0 += wgt * wv.x; a1 += wgt * wv.y; a2 += wgt * wv.z; a3 += wgt * wv.w;
    }
    float4 o = make_float4(a0, a1, a2, a3);
    *(float4*)&Wc[(size_t)h * 2048 + half * 1024 + c0] = o;
    if (half == 0 && threadIdx.x < 64) {
        const int d = threadIdx.x;
        float v = pbu[h * 64 + d] * bk[h * 64 + d] * SC2E;
#pragma unroll
        for (int o2 = 1; o2 < 64; o2 <<= 1) v += __shfl_xor(v, o2);
        if (d == 0) cu[h] = v;
    }
}

// ---------------------------------------------------------------- q/kp/v GEMM
// z=0: q  = hs·Wq^T  (K=1024), out bf16 (acc+bq)*SC2E
// z=1: kp = hp·Wkp^T (K=2048), out bf16 acc+bk
// z=2: v  = hs·Wv^T  (K=1024), out bf16 transposed (B,H,D,N) via LDS epilogue
// A = hp (row stride 2048). 128x128 tile, BK=32, 16 MFMA/wave-iter.
struct QkpvArgs {
    const unsigned short* A;
    const unsigned short* B[3];
    unsigned short* out[3];
    const float* bias[3];
    int K[3];
};
__global__ __launch_bounds__(256) void gemm_qkpv(QkpvArgs g) {
    __shared__ unsigned short As[128 * 32];
    __shared__ unsigned short Bs[128 * 32];
    __shared__ unsigned short Tr[4][64 * 72];
    const int z = blockIdx.z;
    const int K = g.K[z];
    const unsigned short* __restrict__ A = g.A;
    const unsigned short* __restrict__ B = g.B[z];
    const float* __restrict__ bias = g.bias[z];
    const int t = threadIdx.x;
    const int w = t >> 6, lane = t & 63, l15 = lane & 15, quad = lane >> 4;
    const int m0 = blockIdx.x * 128, n0 = blockIdx.y * 128;
    const int wm = (w >> 1) * 64, wn = (w & 1) * 64;

    f32x4 acc[4][4];
#pragma unroll
    for (int i = 0; i < 4; ++i)
#pragma unroll
        for (int j = 0; j < 4; ++j)
#pragma unroll
            for (int r = 0; r < 4; ++r) acc[i][j][r] = 0.f;

    for (int kb = 0; kb < K; kb += 32) {
        __syncthreads();
#pragma unroll
        for (int j = 0; j < 2; ++j) {
            int id = j * 256 + t;
            int row = id >> 2, c4 = (id & 3) * 8;
            gload_lds16(&A[(size_t)(m0 + row) * 2048 + kb + c4], &As[id * 8]);
            gload_lds16(&B[(size_t)(n0 + row) * K + kb + c4], &Bs[id * 8]);
        }
        __syncthreads();
        bf16x8 af[4], bfr[4];
#pragma unroll
        for (int i = 0; i < 4; ++i)
            af[i] = *(const bf16x8*)&As[(wm + i * 16 + l15) * 32 + quad * 8];
#pragma unroll
        for (int j = 0; j < 4; ++j)
            bfr[j] = *(const bf16x8*)&Bs[(wn + j * 16 + l15) * 32 + quad * 8];
#pragma unroll
        for (int i = 0; i < 4; ++i)
#pragma unroll
            for (int j = 0; j < 4; ++j)
                acc[i][j] = __builtin_amdgcn_mfma_f32_16x16x32_bf16(af[i], bfr[j], acc[i][j], 0, 0, 0);
    }

    if (z != 2) {
        const float sc = (z == 0) ? SC2E : 1.f;
        unsigned short* __restrict__ out = g.out[z];
#pragma unroll
        for (int i = 0; i < 4; ++i)
#pragma unroll
            for (int j = 0; j < 4; ++j) {
                const int col = n0 + wn + j * 16 + l15;
                const int row_base = m0 + wm + i * 16 + quad * 4;
                const float bc = bias[col];
#pragma unroll
                for (int r = 0; r < 4; ++r)
                    out[(size_t)(row_base + r) * CC + col] = f2bf((acc[i][j][r] + bc) * sc);
            }
    } else {
        // transpose epilogue: dump wave tile [n_local][m_local] to LDS (wave-
        // private, stride 72 keeps reads 16B-aligned / ~conflict-free), then
        // 128B-contiguous global stores to vt (B,H,D,N).
        unsigned short* __restrict__ out = g.out[2];
#pragma unroll
        for (int i = 0; i < 4; ++i)
#pragma unroll
            for (int j = 0; j < 4; ++j) {
                const int col = n0 + wn + j * 16 + l15;
                const float bc = bias[col];
                union { unsigned short s[4]; uint2 u; } pk;
#pragma unroll
                for (int r = 0; r < 4; ++r) pk.s[r] = f2bf(acc[i][j][r] + bc);
                *(uint2*)&Tr[w][(j * 16 + l15) * 72 + i * 16 + quad * 4] = pk.u;
            }
        const int bI = (m0 + wm) >> 11, nseq0 = (m0 + wm) & 2047;
        const int rl = lane >> 3, cl = (lane & 7) * 8;
#pragma unroll
        for (int pass = 0; pass < 8; ++pass) {
            const int ln = pass * 8 + rl;
            uint4 vv = *(const uint4*)&Tr[w][ln * 72 + cl];
            const int col = n0 + wn + ln;
            const int hh = col >> 6, dd = col & 63;
            *(uint4*)&out[((size_t)(bI * 16 + hh) * 64 + dd) * 2048 + nseq0 + cl] = vv;
        }
    }
}

// ---------------------------------------------------------------- c GEMM
// cb[(b*16+h)*2048+n] = hp[row]·Wc[h] + cu[h]  (K=2048, fp32 Wc, wave/row)
__global__ __launch_bounds__(256) void gemm_c(const unsigned short* __restrict__ hp,
                                              const float* __restrict__ Wc,
                                              const float* __restrict__ cu,
                                              float* __restrict__ cb) {
    const int gw = (blockIdx.x * 256 + threadIdx.x) >> 6;   // row 0..4095
    const int lane = threadIdx.x & 63;
    const unsigned short* rowp = hp + (size_t)gw * 2048;
    float a[32];
#pragma unroll
    for (int c = 0; c < 4; ++c) {
        bf16x8 v = *(const bf16x8*)&rowp[c * 512 + lane * 8];
#pragma unroll
        for (int j = 0; j < 8; ++j) a[c * 8 + j] = bf2f((unsigned short)v[j]);
    }
    float mine = 0.f;
    for (int h = 0; h < HH; ++h) {
        float acc = 0.f;
#pragma unroll
        for (int c = 0; c < 4; ++c) {
            const float* wp = &Wc[(size_t)h * 2048 + c * 512 + lane * 8];
            float4 w0 = *(const float4*)wp;
            float4 w1 = *(const float4*)(wp + 4);
            acc += a[c*8+0]*w0.x + a[c*8+1]*w0.y + a[c*8+2]*w0.z + a[c*8+3]*w0.w
                 + a[c*8+4]*w1.x + a[c*8+5]*w1.y + a[c*8+6]*w1.z + a[c*8+7]*w1.w;
        }
#pragma unroll
        for (int o = 1; o < 64; o <<= 1) acc += __shfl_xor(acc, o);
        if (lane == h) mine = acc + cu[h];
    }
    if (lane < HH) {
        const int b = gw >> 11, n = gw & 2047;
        cb[((size_t)(b * HH + lane)) * NN + n] = mine;
    }
}

// ---------------------------------------------------------------- attention
// Block: (qt,h,z) -> 128 q, 4 waves x 32 q (R4 structure); z = b*2 split:
// b = z>>1, key-half kz = z&1 (kt in [kz*16, kz*16+16)). Fixed-base exp2
// (partials addable). Outputs unnormalized O^T (fp32) + l partials.
#define PST 80
__global__ __launch_bounds__(256) void attn_kernel(const unsigned short* __restrict__ q,
                                                   const unsigned short* __restrict__ kp,
                                                   const unsigned short* __restrict__ vt,
                                                   const float* __restrict__ cb,
                                                   float* __restrict__ opart,
                                                   float* __restrict__ lpart) {
    __shared__ unsigned short Ks[64 * 64];
    __shared__ unsigned short Vs[64 * 64];
    __shared__ unsigned short Ps[4][32 * PST];

    const int t = threadIdx.x;
    const int w = t >> 6, lane = t & 63, l15 = lane & 15, quad = lane >> 4;
    const int qt = blockIdx.x, h = blockIdx.y, z = blockIdx.z;
    const int b = z >> 1, kz = z & 1;
    const int sw = (l15 & 7) * 8;

    bf16x8 qf[2][2];
#pragma unroll
    for (int qb = 0; qb < 2; ++qb) {
        const int qrow = qt * 128 + w * 32 + qb * 16 + l15;
        const size_t qoff = ((size_t)(b * NN + qrow) * HH + h) * DD;
#pragma unroll
        for (int c2 = 0; c2 < 2; ++c2)
            qf[qb][c2] = *(const bf16x8*)&q[qoff + c2 * 32 + quad * 8];
    }

    f32x4 oT[4][2];
    float l_lane[2] = {0.f, 0.f};
#pragma unroll
    for (int db = 0; db < 4; ++db)
#pragma unroll
        for (int qb = 0; qb < 2; ++qb)
#pragma unroll
            for (int r = 0; r < 4; ++r) oT[db][qb][r] = 0.f;

    const size_t kbase = (size_t)b * NN * CC + (size_t)h * DD;
    const size_t vbase = (size_t)(b * HH + h) * DD * NN;
    const size_t cbase = (size_t)(b * HH + h) * NN;

    for (int kt = kz * 16; kt < kz * 16 + 16; ++kt) {
        __syncthreads();
#pragma unroll
        for (int j = 0; j < 2; ++j) {
            int id = j * 256 + t, row = id >> 3, c8 = id & 7;
            int gc = (c8 ^ (row & 7)) * 8;
            gload_lds16(&kp[kbase + (size_t)(kt * 64 + row) * CC + gc], &Ks[id * 8]);
            gload_lds16(&vt[vbase + (size_t)row * NN + kt * 64 + gc], &Vs[id * 8]);
        }
        __syncthreads();

        // S^T (64 keys x 32 q per wave), c-initialized accumulators
        f32x4 s[2][4];
#pragma unroll
        for (int t4 = 0; t4 < 4; ++t4) {
            f32x4 c4 = *(const f32x4*)&cb[cbase + kt * 64 + t4 * 16 + quad * 4];
            s[0][t4] = c4; s[1][t4] = c4;
        }
#pragma unroll
        for (int t4 = 0; t4 < 4; ++t4) {
            const int row = t4 * 16 + l15;
#pragma unroll
            for (int c2 = 0; c2 < 2; ++c2) {
                bf16x8 kf = *(const bf16x8*)&Ks[row * 64 + ((c2 * 4 + quad) * 8 ^ sw)];
#pragma unroll
                for (int qb = 0; qb < 2; ++qb)
                    s[qb][t4] = __builtin_amdgcn_mfma_f32_16x16x32_bf16(kf, qf[qb][c2], s[qb][t4], 0, 0, 0);
            }
        }

        // fixed-base exp2 softmax
#pragma unroll
        for (int qb = 0; qb < 2; ++qb) {
            float rs = 0.f;
#pragma unroll
            for (int t4 = 0; t4 < 4; ++t4)
#pragma unroll
                for (int r = 0; r < 4; ++r) {
                    float pv = exp2f(s[qb][t4][r]);
                    s[qb][t4][r] = pv;
                    rs += pv;
                }
            l_lane[qb] += rs;
#pragma unroll
            for (int t4 = 0; t4 < 4; ++t4) {
                uint2 pk;
                pk.x = pk2(s[qb][t4][0], s[qb][t4][1]);
                pk.y = pk2(s[qb][t4][2], s[qb][t4][3]);
                *(uint2*)&Ps[w][(qb * 16 + l15) * PST + t4 * 16 + quad * 4] = pk;
            }
        }
        // no barrier: Ps[w] is wave-private

        // O^T += V^T · P
#pragma unroll
        for (int c2 = 0; c2 < 2; ++c2) {
            bf16x8 pf[2];
#pragma unroll
            for (int qb = 0; qb < 2; ++qb)
                pf[qb] = *(const bf16x8*)&Ps[w][(qb * 16 + l15) * PST + c2 * 32 + quad * 8];
#pragma unroll
            for (int db = 0; db < 4; ++db) {
                bf16x8 vf = *(const bf16x8*)&Vs[(db * 16 + l15) * 64 + ((c2 * 4 + quad) * 8 ^ sw)];
#pragma unroll
                for (int qb = 0; qb < 2; ++qb)
                    oT[db][qb] = __builtin_amdgcn_mfma_f32_16x16x32_bf16(vf, pf[qb], oT[db][qb], 0, 0, 0);
            }
        }
    }

    // epilogue: unnormalized O^T + l partials
#pragma unroll
    for (int qb = 0; qb < 2; ++qb) {
        float l = l_lane[qb];
        l += __shfl_xor(l, 16);
        l += __shfl_xor(l, 32);
        const int qrow = qt * 128 + w * 32 + qb * 16 + l15;
        const size_t ob = (((size_t)(kz * 2 + b) * HH + h) * NN + qrow) * DD;
#pragma unroll
        for (int db = 0; db < 4; ++db)
            *(f32x4*)&opart[ob + db * 16 + quad * 4] = oT[db][qb];
        if (quad == 0)
            lpart[((size_t)(kz * 2 + b) * HH + h) * NN + qrow] = l;
    }
}

// ---------------------------------------------------------------- merge
// att[b][n][h][d] = bf16( (O0+O1) / (l0+l1) )
__global__ __launch_bounds__(256) void merge_kernel(const float* __restrict__ opart,
                                                    const float* __restrict__ lpart,
                                                    unsigned short* __restrict__ att) {
    const int idx = blockIdx.x * 256 + threadIdx.x;
    const int d4 = idx & 15, qn = (idx >> 4) & 2047, h = (idx >> 15) & 15, b = idx >> 19;
    const size_t i0 = (((size_t)b * HH + h) * NN + qn) * DD + d4 * 4;
    const size_t i1 = (((size_t)(2 + b) * HH + h) * NN + qn) * DD + d4 * 4;
    f32x4 o0 = *(const f32x4*)&opart[i0];
    f32x4 o1 = *(const f32x4*)&opart[i1];
    const float l = lpart[((size_t)b * HH + h) * NN + qn] +
                    lpart[((size_t)(2 + b) * HH + h) * NN + qn];
    const float inv = 1.f / l;
    uint2 pk;
    pk.x = pk2((o0[0] + o1[0]) * inv, (o0[1] + o1[1]) * inv);
    pk.y = pk2((o0[2] + o1[2]) * inv, (o0[3] + o1[3]) * inv);
    *(uint2*)&att[(((size_t)b * NN + qn) * HH + h) * DD + d4 * 4] = pk;
}

// ---------------------------------------------------------------- out GEMM
// out fp32 = att·Wo^T + bo. 128x64 tile (512 blocks = 2/CU).
__global__ __launch_bounds__(256) void gemm_out(const unsigned short* __restrict__ A,
                                                const unsigned short* __restrict__ B,
                                                float* __restrict__ out,
                                                const float* __restrict__ bias) {
    constexpr int K = CC;
    __shared__ unsigned short As[128 * 32];
    __shared__ unsigned short Bs[64 * 32];
    const int t = threadIdx.x;
    const int w = t >> 6, lane = t & 63, l15 = lane & 15, quad = lane >> 4;
    const int m0 = blockIdx.x * 128, n0 = blockIdx.y * 64;
    const int wm = (w >> 1) * 64, wn = (w & 1) * 32;

    f32x4 acc[4][2];
#pragma unroll
    for (int i = 0; i < 4; ++i)
#pragma unroll
        for (int j = 0; j < 2; ++j)
#pragma unroll
            for (int r = 0; r < 4; ++r) acc[i][j][r] = 0.f;

    for (int kb = 0; kb < K; kb += 32) {
        __syncthreads();
#pragma unroll
        for (int j = 0; j < 2; ++j) {
            int id = j * 256 + t;
            int row = id >> 2, c4 = (id & 3) * 8;
            gload_lds16(&A[(size_t)(m0 + row) * K + kb + c4], &As[id * 8]);
        }
        {
            int row = t >> 2, c4 = (t & 3) * 8;
            gload_lds16(&B[(size_t)(n0 + row) * K + kb + c4], &Bs[t * 8]);
        }
        __syncthreads();
        bf16x8 af[4], bfr[2];
#pragma unroll
        for (int i = 0; i < 4; ++i)
            af[i] = *(const bf16x8*)&As[(wm + i * 16 + l15) * 32 + quad * 8];
#pragma unroll
        for (int j = 0; j < 2; ++j)
            bfr[j] = *(const bf16x8*)&Bs[(wn + j * 16 + l15) * 32 + quad * 8];
#pragma unroll
        for (int i = 0; i < 4; ++i)
#pragma unroll
            for (int j = 0; j < 2; ++j)
                acc[i][j] = __builtin_amdgcn_mfma_f32_16x16x32_bf16(af[i], bfr[j], acc[i][j], 0, 0, 0);
    }

#pragma unroll
    for (int i = 0; i < 4; ++i)
#pragma unroll
        for (int j = 0; j < 2; ++j) {
            const int col = n0 + wn + j * 16 + l15;
            const int row_base = m0 + wm + i * 16 + quad * 4;
            const float bc = bias[col];
#pragma unroll
            for (int r = 0; r < 4; ++r)
                out[(size_t)(row_base + r) * CC + col] = acc[i][j][r] + bc;
        }
}

// ---------------------------------------------------------------- launch
extern "C" void kernel_launch(void* const* d_in, const int* in_sizes, int n_in,
                              void* d_out, int out_size, void* d_ws, size_t ws_size,
                              hipStream_t stream) {
    const float* hs   = (const float*)d_in[0];
    const float* pos  = (const float*)d_in[1];
    const float* Wq   = (const float*)d_in[2];
    const float* bq   = (const float*)d_in[3];
    const float* Wk   = (const float*)d_in[4];
    const float* bk   = (const float*)d_in[5];
    const float* Wv   = (const float*)d_in[6];
    const float* bv   = (const float*)d_in[7];
    const float* Wpos = (const float*)d_in[8];
    const float* pbu  = (const float*)d_in[9];
    const float* pbv  = (const float*)d_in[10];
    const float* Wo   = (const float*)d_in[11];
    const float* bo   = (const float*)d_in[12];
    float* out = (float*)d_out;

    // workspace layout (bytes). Front 33.55 MB: phase-1 hp/wq/wkp/wv, later
    // reused as opart (attn runs strictly after all phase-1 consumers).
    char* base = (char*)d_ws;
    unsigned short* hp    = (unsigned short*)(base);               // 16.78 MB
    unsigned short* wqb   = (unsigned short*)(base + 16777216);    //  2 MB
    unsigned short* wkpb  = (unsigned short*)(base + 18874368);    //  4 MB
    unsigned short* wvb   = (unsigned short*)(base + 23068672);    //  2 MB
    float*          opart = (float*)(base);                        // 33.55 MB
    unsigned short* wob   = (unsigned short*)(base + 33554432);    //  2 MB
    float*          Wc    = (float*)(base + 35651584);             // 128 KB
    float*          cu    = (float*)(base + 35782656);             // 512 B
    float*          cb    = (float*)(base + 35783168);             // 256 KB
    unsigned short* qsb   = (unsigned short*)(base + 36045312);    // 8.39 MB
    unsigned short* kpb   = (unsigned short*)(base + 44433920);    // 8.39 MB
    unsigned short* vtb   = (unsigned short*)(base + 52822528);    // 8.39 MB
    float*          lpart = (float*)(base + 61211136);             // 512 KB
    unsigned short* attb  = qsb;   // qsb dead once attn finished

    CastArgs ca;
    ca.src[0] = hs;   ca.dst[0] = hp;   ca.rows[0] = 4096; ca.stride[0] = 2048; ca.col0[0] = 0;
    ca.src[1] = pos;  ca.dst[1] = hp;   ca.rows[1] = 4096; ca.stride[1] = 2048; ca.col0[1] = 1024;
    ca.src[2] = Wq;   ca.dst[2] = wqb;  ca.rows[2] = 1024; ca.stride[2] = 1024; ca.col0[2] = 0;
    ca.src[3] = Wk;   ca.dst[3] = wkpb; ca.rows[3] = 1024; ca.stride[3] = 2048; ca.col0[3] = 0;
    ca.src[4] = Wpos; ca.dst[4] = wkpb; ca.rows[4] = 1024; ca.stride[4] = 2048; ca.col0[4] = 1024;
    ca.src[5] = Wv;   ca.dst[5] = wvb;  ca.rows[5] = 1024; ca.stride[5] = 1024; ca.col0[5] = 0;
    ca.src[6] = Wo;   ca.dst[6] = wob;  ca.rows[6] = 1024; ca.stride[6] = 1024; ca.col0[6] = 0;
    dim3 cgrid(4096, 7);
    cast_all<<<cgrid, 256, 0, stream>>>(ca);

    dim3 pgrid(HH, 2);
    prep<<<pgrid, 256, 0, stream>>>(Wk, Wpos, pbu, pbv, bk, Wc, cu);

    QkpvArgs qa;
    qa.A = hp;
    qa.B[0] = wqb;  qa.out[0] = qsb; qa.bias[0] = bq; qa.K[0] = 1024;
    qa.B[1] = wkpb; qa.out[1] = kpb; qa.bias[1] = bk; qa.K[1] = 2048;
    qa.B[2] = wvb;  qa.out[2] = vtb; qa.bias[2] = bv; qa.K[2] = 1024;
    dim3 ggrid(MM / 128, CC / 128, 3);
    gemm_qkpv<<<ggrid, 256, 0, stream>>>(qa);

    gemm_c<<<MM / 4, 256, 0, stream>>>(hp, Wc, cu, cb);

    dim3 agrid(NN / 128, HH, 4);
    attn_kernel<<<agrid, 256, 0, stream>>>(qsb, kpb, vtb, cb, opart, lpart);

    merge_kernel<<<(BB * NN * HH * DD / 4) / 256, 256, 0, stream>>>(opart, lpart, attb);

    dim3 ogrid(MM / 128, CC / 64);
    gemm_out<<<ogrid, 256, 0, stream>>>(attb, wob, out, bo);
}

// Round 8
// 264.475 us; speedup vs baseline: 1.1527x; 1.1527x over previous
//
#include <hip/hip_runtime.h>
#include <hip/hip_bf16.h>

// WhaleAttention: B=2, N=2048, C=1024, H=16, D=64, SCALE=1/8
// R8 = best-of-session: R6 balanced 4-z GEMM batch (+LDS-coalesced v^T
// epilogue), R6 fuse_kpc, attn = R4 32q/wave shape + fixed-base exp2 +
// hoisted c-init loads, gemm_out at 2 blocks/CU. 5 dispatches.

typedef short bf16x8 __attribute__((ext_vector_type(8)));
typedef float f32x4 __attribute__((ext_vector_type(4)));

#define BB 2
#define NN 2048
#define CC 1024
#define HH 16
#define DD 64
#define MM (BB * NN)      // 4096 rows
#define SC2E 0.18033688f  // SCALE * log2(e)

__device__ __forceinline__ unsigned short f2bf(float f) {
    union { float f; unsigned int u; } x; x.f = f;
    unsigned int r = x.u + 0x7FFFu + ((x.u >> 16) & 1u);
    return (unsigned short)(r >> 16);
}

__device__ __forceinline__ float bf2f(unsigned short s) {
    union { unsigned int u; float f; } x; x.u = ((unsigned int)s) << 16;
    return x.f;
}

__device__ __forceinline__ unsigned int pk2(float a, float b) {
    __hip_bfloat162 h = __float22bfloat162_rn(make_float2(a, b));
    unsigned int u; __builtin_memcpy(&u, &h, 4); return u;
}

typedef __attribute__((address_space(1))) const unsigned int* gas1_t;
typedef __attribute__((address_space(3))) unsigned int* las3_t;

__device__ __forceinline__ void gload_lds16(const unsigned short* g, unsigned short* l) {
    __builtin_amdgcn_global_load_lds((gas1_t)g, (las3_t)l, 16, 0, 0);
}

// ---------------------------------------------------------------- cast kernel
struct CastArgs {
    const float* src[7];
    unsigned short* dst[7];
    int n4[7];
};
__global__ __launch_bounds__(256) void cast_all(CastArgs a) {
    const int seg = blockIdx.y;
    const int i = blockIdx.x * 256 + threadIdx.x;
    if (i >= a.n4[seg]) return;
    float4 v = ((const float4*)a.src[seg])[i];
    uint2 u;
    u.x = pk2(v.x, v.y);
    u.y = pk2(v.z, v.w);
    ((uint2*)a.dst[seg])[i] = u;
}

// ---------------------------------------------------------------- batched GEMM
// z=0: q (bf16, (acc+bq)*SC2E), z=1: k (+bk), z=2: v transposed (B,H,D,N)
// via LDS transpose epilogue, z=3: p (plain). 128x128 tile, BK=32,
// 16 MFMA/wave-iter. 1024 blocks = 4/CU (balanced, all K=1024).
struct GemmBatch {
    const unsigned short* A[4];
    const unsigned short* B[4];
    unsigned short* out[4];
    const float* bias[4];
};
__global__ __launch_bounds__(256) void gemm_qkvp(GemmBatch g) {
    constexpr int K = CC;
    __shared__ unsigned short Sh[2 * 128 * 32];   // As | Bs ; reused as Tr
    unsigned short* As = Sh;
    unsigned short* Bs = Sh + 128 * 32;
    const int z = blockIdx.z;
    const unsigned short* __restrict__ A = g.A[z];
    const unsigned short* __restrict__ B = g.B[z];
    unsigned short* __restrict__ out = g.out[z];
    const float* __restrict__ bias = g.bias[z];

    const int t = threadIdx.x;
    const int w = t >> 6, lane = t & 63, l15 = lane & 15, quad = lane >> 4;
    const int m0 = blockIdx.x * 128, n0 = blockIdx.y * 128;
    const int wm = (w >> 1) * 64, wn = (w & 1) * 64;

    f32x4 acc[4][4];
#pragma unroll
    for (int i = 0; i < 4; ++i)
#pragma unroll
        for (int j = 0; j < 4; ++j)
#pragma unroll
            for (int r = 0; r < 4; ++r) acc[i][j][r] = 0.f;

    for (int kb = 0; kb < K; kb += 32) {
        __syncthreads();
#pragma unroll
        for (int j = 0; j < 2; ++j) {
            int id = j * 256 + t;
            int row = id >> 2, c4 = (id & 3) * 8;
            gload_lds16(&A[(size_t)(m0 + row) * K + kb + c4], &As[id * 8]);
            gload_lds16(&B[(size_t)(n0 + row) * K + kb + c4], &Bs[id * 8]);
        }
        __syncthreads();
        bf16x8 af[4], bfr[4];
#pragma unroll
        for (int i = 0; i < 4; ++i)
            af[i] = *(const bf16x8*)&As[(wm + i * 16 + l15) * 32 + quad * 8];
#pragma unroll
        for (int j = 0; j < 4; ++j)
            bfr[j] = *(const bf16x8*)&Bs[(wn + j * 16 + l15) * 32 + quad * 8];
#pragma unroll
        for (int i = 0; i < 4; ++i)
#pragma unroll
            for (int j = 0; j < 4; ++j)
                acc[i][j] = __builtin_amdgcn_mfma_f32_16x16x32_bf16(af[i], bfr[j], acc[i][j], 0, 0, 0);
    }

    if (z != 2) {
        const float sc = (z == 0) ? SC2E : 1.f;
#pragma unroll
        for (int i = 0; i < 4; ++i)
#pragma unroll
            for (int j = 0; j < 4; ++j) {
                const int col = n0 + wn + j * 16 + l15;
                const int row_base = m0 + wm + i * 16 + quad * 4;
                const float bc = bias ? bias[col] : 0.f;
#pragma unroll
                for (int r = 0; r < 4; ++r)
                    out[(size_t)(row_base + r) * CC + col] = f2bf((acc[i][j][r] + bc) * sc);
            }
    } else {
        // v^T epilogue: per-wave 16-col chunks through LDS (reusing As/Bs
        // region; per-wave 16x72 = 2304B, 4 waves = 9.2KB < 16KB), then
        // 128B-contiguous dwordx4 stores to vt (B,H,D,N).
        __syncthreads();    // all waves done reading As/Bs fragments
        unsigned short* Tr = &Sh[w * 1152];   // 16 cols x stride 72
        const int bI = (m0 + wm) >> 11, nseq0 = (m0 + wm) & 2047;
        const int colL = lane >> 3;           // 0..7
        const int mL = (lane & 7) * 8;        // 0..56
#pragma unroll
        for (int j = 0; j < 4; ++j) {
            const int col = n0 + wn + j * 16 + l15;
            const float bc = bias[col];
#pragma unroll
            for (int i = 0; i < 4; ++i) {
                uint2 pk;
                pk.x = pk2(acc[i][j][0] + bc, acc[i][j][1] + bc);
                pk.y = pk2(acc[i][j][2] + bc, acc[i][j][3] + bc);
                *(uint2*)&Tr[l15 * 72 + i * 16 + quad * 4] = pk;
            }
            // same-wave DS ops are in-order; reads below see the writes above
#pragma unroll
            for (int p = 0; p < 2; ++p) {
                const int cl = p * 8 + colL;
                uint4 vv = *(const uint4*)&Tr[cl * 72 + mL];
                const int gcol = n0 + wn + j * 16 + cl;
                const int hh = gcol >> 6, dd = gcol & 63;
                *(uint4*)&out[((size_t)(bI * 16 + hh) * 64 + dd) * 2048 + nseq0 + mL] = vv;
            }
        }
    }
}

// ---------------------------------------------------------------- fuse kp + c
// One wave per (row, h): kp = k + p (bf16) and c = SC2E*(u·k + v·p) (fp32).
__global__ __launch_bounds__(256) void fuse_kpc(const unsigned short* __restrict__ k,
                                                const unsigned short* __restrict__ pp,
                                                const float* __restrict__ pbu,
                                                const float* __restrict__ pbv,
                                                unsigned short* __restrict__ kp,
                                                float* __restrict__ c) {
    const int gw = (blockIdx.x * 256 + threadIdx.x) >> 6;
    const int lane = threadIdx.x & 63;
    const int row = gw >> 4, h = gw & 15;          // row = b*N + n
    const size_t off = (size_t)row * CC + h * 64 + lane;
    const float kv = bf2f(k[off]), pv = bf2f(pp[off]);
    kp[off] = f2bf(kv + pv);
    float val = pbu[h * 64 + lane] * kv + pbv[h * 64 + lane] * pv;
#pragma unroll
    for (int o = 1; o < 64; o <<= 1) val += __shfl_xor(val, o);
    if (lane == 0) {
        const int b = row >> 11, n = row & 2047;
        c[((size_t)(b * HH + h)) * NN + n] = val * SC2E;
    }
}

// ---------------------------------------------------------------- attention
// Block: (qt,h,b) -> 128 q rows, 4 waves x 32 q (the R4 shape, best measured).
//   S^T[key][q] = KP·Q^T, accumulator initialized with c[key] (loads hoisted
//   above the barrier); P = exp2(S) fixed base; per-wave LDS round-trip;
//   O^T[d][q] = V^T·P; O /= l at the end; direct bf16 output.
#define PST 80
__global__ __launch_bounds__(256) void attn_kernel(const unsigned short* __restrict__ q,
                                                   const unsigned short* __restrict__ kp,
                                                   const unsigned short* __restrict__ vt,
                                                   const float* __restrict__ cb,
                                                   unsigned short* __restrict__ att) {
    __shared__ unsigned short Ks[64 * 64];
    __shared__ unsigned short Vs[64 * 64];
    __shared__ unsigned short Ps[4][32 * PST];

    const int t = threadIdx.x;
    const int w = t >> 6, lane = t & 63, l15 = lane & 15, quad = lane >> 4;
    const int qt = blockIdx.x, h = blockIdx.y, b = blockIdx.z;
    const int sw = (l15 & 7) * 8;

    bf16x8 qf[2][2];
#pragma unroll
    for (int qb = 0; qb < 2; ++qb) {
        const int qrow = qt * 128 + w * 32 + qb * 16 + l15;
        const size_t qoff = ((size_t)(b * NN + qrow) * HH + h) * DD;
#pragma unroll
        for (int c2 = 0; c2 < 2; ++c2)
            qf[qb][c2] = *(const bf16x8*)&q[qoff + c2 * 32 + quad * 8];
    }

    f32x4 oT[4][2];
    float l_lane[2] = {0.f, 0.f};
#pragma unroll
    for (int db = 0; db < 4; ++db)
#pragma unroll
        for (int qb = 0; qb < 2; ++qb)
#pragma unroll
            for (int r = 0; r < 4; ++r) oT[db][qb][r] = 0.f;

    const size_t kbase = (size_t)b * NN * CC + (size_t)h * DD;
    const size_t vbase = (size_t)(b * HH + h) * DD * NN;
    const size_t cbase = (size_t)(b * HH + h) * NN;

    for (int kt = 0; kt < NN / 64; ++kt) {
        // c-init loads hoisted above the barrier (independent of LDS staging)
        f32x4 c4[4];
#pragma unroll
        for (int t4 = 0; t4 < 4; ++t4)
            c4[t4] = *(const f32x4*)&cb[cbase + kt * 64 + t4 * 16 + quad * 4];

        __syncthreads();
#pragma unroll
        for (int j = 0; j < 2; ++j) {
            int id = j * 256 + t, row = id >> 3, c8 = id & 7;
            int gc = (c8 ^ (row & 7)) * 8;
            gload_lds16(&kp[kbase + (size_t)(kt * 64 + row) * CC + gc], &Ks[id * 8]);
            gload_lds16(&vt[vbase + (size_t)row * NN + kt * 64 + gc], &Vs[id * 8]);
        }
        __syncthreads();

        // S^T (64 keys x 32 q per wave), c-initialized accumulators
        f32x4 s[2][4];
#pragma unroll
        for (int t4 = 0; t4 < 4; ++t4) {
            s[0][t4] = c4[t4];
            s[1][t4] = c4[t4];
        }
#pragma unroll
        for (int t4 = 0; t4 < 4; ++t4) {
            const int row = t4 * 16 + l15;
#pragma unroll
            for (int c2 = 0; c2 < 2; ++c2) {
                bf16x8 kf = *(const bf16x8*)&Ks[row * 64 + ((c2 * 4 + quad) * 8 ^ sw)];
#pragma unroll
                for (int qb = 0; qb < 2; ++qb)
                    s[qb][t4] = __builtin_amdgcn_mfma_f32_16x16x32_bf16(kf, qf[qb][c2], s[qb][t4], 0, 0, 0);
            }
        }

        // fixed-base exp2 softmax; l reduced once at the end
#pragma unroll
        for (int qb = 0; qb < 2; ++qb) {
            float rs = 0.f;
#pragma unroll
            for (int t4 = 0; t4 < 4; ++t4)
#pragma unroll
                for (int r = 0; r < 4; ++r) {
                    float pv = exp2f(s[qb][t4][r]);
                    s[qb][t4][r] = pv;
                    rs += pv;
                }
            l_lane[qb] += rs;
#pragma unroll
            for (int t4 = 0; t4 < 4; ++t4) {
                uint2 pk;
                pk.x = pk2(s[qb][t4][0], s[qb][t4][1]);
                pk.y = pk2(s[qb][t4][2], s[qb][t4][3]);
                *(uint2*)&Ps[w][(qb * 16 + l15) * PST + t4 * 16 + quad * 4] = pk;
            }
        }
        // no barrier: Ps[w] is wave-private

        // O^T += V^T · P
#pragma unroll
        for (int c2 = 0; c2 < 2; ++c2) {
            bf16x8 pf[2];
#pragma unroll
            for (int qb = 0; qb < 2; ++qb)
                pf[qb] = *(const bf16x8*)&Ps[w][(qb * 16 + l15) * PST + c2 * 32 + quad * 8];
#pragma unroll
            for (int db = 0; db < 4; ++db) {
                bf16x8 vf = *(const bf16x8*)&Vs[(db * 16 + l15) * 64 + ((c2 * 4 + quad) * 8 ^ sw)];
#pragma unroll
                for (int qb = 0; qb < 2; ++qb)
                    oT[db][qb] = __builtin_amdgcn_mfma_f32_16x16x32_bf16(vf, pf[qb], oT[db][qb], 0, 0, 0);
            }
        }
    }

    // epilogue: normalize and write bf16 (B,N,H,D)
#pragma unroll
    for (int qb = 0; qb < 2; ++qb) {
        float l = l_lane[qb];
        l += __shfl_xor(l, 16);
        l += __shfl_xor(l, 32);
        const float inv = 1.f / l;
        const int qrow = qt * 128 + w * 32 + qb * 16 + l15;
        const size_t ob = ((size_t)(b * NN + qrow) * HH + h) * DD;
#pragma unroll
        for (int db = 0; db < 4; ++db) {
            uint2 pk;
            pk.x = pk2(oT[db][qb][0] * inv, oT[db][qb][1] * inv);
            pk.y = pk2(oT[db][qb][2] * inv, oT[db][qb][3] * inv);
            *(uint2*)&att[ob + db * 16 + quad * 4] = pk;
        }
    }
}

// ---------------------------------------------------------------- out GEMM
// out fp32 = att·Wo^T + bo. 128x64 tile -> 512 blocks = 2/CU.
__global__ __launch_bounds__(256) void gemm_out(const unsigned short* __restrict__ A,
                                                const unsigned short* __restrict__ B,
                                                float* __restrict__ out,
                                                const float* __restrict__ bias) {
    constexpr int K = CC;
    __shared__ unsigned short As[128 * 32];
    __shared__ unsigned short Bs[64 * 32];
    const int t = threadIdx.x;
    const int w = t >> 6, lane = t & 63, l15 = lane & 15, quad = lane >> 4;
    const int m0 = blockIdx.x * 128, n0 = blockIdx.y * 64;
    const int wm = (w >> 1) * 64, wn = (w & 1) * 32;

    f32x4 acc[4][2];
#pragma unroll
    for (int i = 0; i < 4; ++i)
#pragma unroll
        for (int j = 0; j < 2; ++j)
#pragma unroll
            for (int r = 0; r < 4; ++r) acc[i][j][r] = 0.f;

    for (int kb = 0; kb < K; kb += 32) {
        __syncthreads();
#pragma unroll
        for (int j = 0; j < 2; ++j) {
            int id = j * 256 + t;
            int row = id >> 2, c4 = (id & 3) * 8;
            gload_lds16(&A[(size_t)(m0 + row) * K + kb + c4], &As[id * 8]);
        }
        {
            int row = t >> 2, c4 = (t & 3) * 8;
            gload_lds16(&B[(size_t)(n0 + row) * K + kb + c4], &Bs[t * 8]);
        }
        __syncthreads();
        bf16x8 af[4], bfr[2];
#pragma unroll
        for (int i = 0; i < 4; ++i)
            af[i] = *(const bf16x8*)&As[(wm + i * 16 + l15) * 32 + quad * 8];
#pragma unroll
        for (int j = 0; j < 2; ++j)
            bfr[j] = *(const bf16x8*)&Bs[(wn + j * 16 + l15) * 32 + quad * 8];
#pragma unroll
        for (int i = 0; i < 4; ++i)
#pragma unroll
            for (int j = 0; j < 2; ++j)
                acc[i][j] = __builtin_amdgcn_mfma_f32_16x16x32_bf16(af[i], bfr[j], acc[i][j], 0, 0, 0);
    }

#pragma unroll
    for (int i = 0; i < 4; ++i)
#pragma unroll
        for (int j = 0; j < 2; ++j) {
            const int col = n0 + wn + j * 16 + l15;
            const int row_base = m0 + wm + i * 16 + quad * 4;
            const float bc = bias[col];
#pragma unroll
            for (int r = 0; r < 4; ++r)
                out[(size_t)(row_base + r) * CC + col] = acc[i][j][r] + bc;
        }
}

// ---------------------------------------------------------------- launch
extern "C" void kernel_launch(void* const* d_in, const int* in_sizes, int n_in,
                              void* d_out, int out_size, void* d_ws, size_t ws_size,
                              hipStream_t stream) {
    const float* hs   = (const float*)d_in[0];
    const float* pos  = (const float*)d_in[1];
    const float* Wq   = (const float*)d_in[2];
    const float* bq   = (const float*)d_in[3];
    const float* Wk   = (const float*)d_in[4];
    const float* bk   = (const float*)d_in[5];
    const float* Wv   = (const float*)d_in[6];
    const float* bv   = (const float*)d_in[7];
    const float* Wpos = (const float*)d_in[8];
    const float* pbu  = (const float*)d_in[9];
    const float* pbv  = (const float*)d_in[10];
    const float* Wo   = (const float*)d_in[11];
    const float* bo   = (const float*)d_in[12];
    float* out = (float*)d_out;

    const size_t nHS = (size_t)MM * CC;
    const size_t nW  = (size_t)CC * CC;

    unsigned short* p = (unsigned short*)d_ws;
    unsigned short* hsb  = p;            p += nHS;
    unsigned short* posb = p;            p += nHS;
    unsigned short* wqb  = p;            p += nW;
    unsigned short* wkb  = p;            p += nW;
    unsigned short* wvb  = p;            p += nW;
    unsigned short* wpb  = p;            p += nW;
    unsigned short* wob  = p;            p += nW;
    unsigned short* qsb  = p;            p += nHS;
    unsigned short* kbf  = p;            p += nHS;
    unsigned short* pbf  = p;            p += nHS;
    unsigned short* kpb  = p;            p += nHS;
    unsigned short* vtb  = p;            p += nHS;
    float* cb = (float*)p;               p += (size_t)BB * HH * NN * 2;
    unsigned short* attb = hsb;          // alias: hsb dead after gemm_qkvp

    CastArgs ca;
    ca.src[0] = hs;   ca.dst[0] = hsb;  ca.n4[0] = (int)(nHS / 4);
    ca.src[1] = pos;  ca.dst[1] = posb; ca.n4[1] = (int)(nHS / 4);
    ca.src[2] = Wq;   ca.dst[2] = wqb;  ca.n4[2] = (int)(nW / 4);
    ca.src[3] = Wk;   ca.dst[3] = wkb;  ca.n4[3] = (int)(nW / 4);
    ca.src[4] = Wv;   ca.dst[4] = wvb;  ca.n4[4] = (int)(nW / 4);
    ca.src[5] = Wpos; ca.dst[5] = wpb;  ca.n4[5] = (int)(nW / 4);
    ca.src[6] = Wo;   ca.dst[6] = wob;  ca.n4[6] = (int)(nW / 4);
    dim3 cgrid((unsigned)(nHS / 4 / 256), 7);
    cast_all<<<cgrid, 256, 0, stream>>>(ca);

    GemmBatch gb;
    gb.A[0] = hsb;  gb.B[0] = wqb; gb.out[0] = qsb; gb.bias[0] = bq;
    gb.A[1] = hsb;  gb.B[1] = wkb; gb.out[1] = kbf; gb.bias[1] = bk;
    gb.A[2] = hsb;  gb.B[2] = wvb; gb.out[2] = vtb; gb.bias[2] = bv;
    gb.A[3] = posb; gb.B[3] = wpb; gb.out[3] = pbf; gb.bias[3] = nullptr;
    dim3 ggrid(MM / 128, CC / 128, 4);
    gemm_qkvp<<<ggrid, 256, 0, stream>>>(gb);

    fuse_kpc<<<MM * HH / 4, 256, 0, stream>>>(kbf, pbf, pbu, pbv, kpb, cb);

    dim3 agrid(NN / 128, HH, BB);
    attn_kernel<<<agrid, 256, 0, stream>>>(qsb, kpb, vtb, cb, attb);

    dim3 ogrid(MM / 128, CC / 64);
    gemm_out<<<ogrid, 256, 0, stream>>>(attb, wob, out, bo);
}